// Round 1
// baseline (158.298 us; speedup 1.0000x reference)
//
#include <hip/hip_runtime.h>
#include <hip/hip_bf16.h>

// QueryGrouper: ball_query (first-K-in-index-order within radius) + grouping.
// B=4, N=8192, M=2048, C=128, K=32, radius=0.1, use_xyz=1 (derived from out_size).

#define K_NEIGH 32
// f32(0.010000000000000002) — matches JAX weak-typed radius*radius threshold bit-exactly.
#define R2_F32 0.009999999776482582f

__global__ __launch_bounds__(256) void ball_query_kernel(
    const float* __restrict__ xyz,      // (B,3,N)
    const float* __restrict__ new_xyz,  // (B,3,M)
    int* __restrict__ idxb,             // (B*M, K)
    int N, int M)
{
    const int wave = threadIdx.x >> 6;
    const int lane = threadIdx.x & 63;
    const int q = blockIdx.x * 4 + wave;           // query id in [0, B*M)
    const int b = q / M;
    const int m = q - b * M;

    const float* xb = xyz + (size_t)b * 3 * N;
    const float* nb = new_xyz + (size_t)b * 3 * M;
    const float qx = nb[m];
    const float qy = nb[M + m];
    const float qz = nb[2 * M + m];

    int* out = idxb + (size_t)q * K_NEIGH;

    int cnt = 0;
    int first_found = 0;   // pad value: first in-ball index, or 0 if none

    for (int t = 0; t < N; t += 64) {
        const int i = t + lane;
        // match JAX: sub, square (no FMA), left-to-right sum, all f32 RN
        const float dx = xb[i]         - qx;
        const float dy = xb[N + i]     - qy;
        const float dz = xb[2 * N + i] - qz;
        const float d2 = __fadd_rn(__fadd_rn(__fmul_rn(dx, dx), __fmul_rn(dy, dy)),
                                   __fmul_rn(dz, dz));
        const bool in_ball = d2 < R2_F32;
        const unsigned long long mask = __ballot(in_ball);
        if (mask) {
            if (cnt == 0) {
                first_found = t + (__ffsll((unsigned long long)mask) - 1);
            }
            if (in_ball) {
                const int pos = cnt + __popcll(mask & ((1ull << lane) - 1ull));
                if (pos < K_NEIGH) out[pos] = i;
            }
            cnt += __popcll(mask);
            if (cnt >= K_NEIGH) break;   // first K found (in index order)
        }
    }

    if (cnt < K_NEIGH) {
        if (lane >= cnt && lane < K_NEIGH) out[lane] = first_found;
    }
}

// 256 threads = 8 queries x 32 slots. tid -> (m_local, k); stores per channel are
// one contiguous 1KB run per block.
__global__ __launch_bounds__(256) void gather_kernel(
    const float* __restrict__ xyz,      // (B,3,N)
    const float* __restrict__ new_xyz,  // (B,3,M)
    const float* __restrict__ feat,     // (B,C,N)
    const int* __restrict__ idxb,       // (B*M,K)
    float* __restrict__ out0,           // (B, 3+C or C, M, K)
    float* __restrict__ out1,           // (B, 3, M, K)
    int N, int M, int C, int use_xyz)
{
    const int tid = threadIdx.x;
    const int k = tid & 31;
    const int mloc = tid >> 5;

    const int mchunks = M >> 3;
    const int b = blockIdx.x / mchunks;
    const int m = (blockIdx.x - b * mchunks) * 8 + mloc;
    const int q = b * M + m;

    const int j = idxb[(size_t)q * K_NEIGH + k];

    const size_t xb = (size_t)b * 3 * N;
    const size_t nb = (size_t)b * 3 * M;
    const float gx = xyz[xb + j]         - new_xyz[nb + m];
    const float gy = xyz[xb + N + j]     - new_xyz[nb + M + m];
    const float gz = xyz[xb + 2 * N + j] - new_xyz[nb + 2 * M + m];

    const size_t MK = (size_t)M * K_NEIGH;
    const size_t o1 = (size_t)b * 3 * MK + (size_t)m * K_NEIGH + k;
    out1[o1]          = gx;
    out1[o1 + MK]     = gy;
    out1[o1 + 2 * MK] = gz;

    const int CO = use_xyz ? (C + 3) : C;
    size_t o0 = (size_t)b * CO * MK + (size_t)m * K_NEIGH + k;
    if (use_xyz) {
        out0[o0]          = gx;
        out0[o0 + MK]     = gy;
        out0[o0 + 2 * MK] = gz;
        o0 += 3 * MK;
    }

    const float* fb = feat + (size_t)b * C * N;
    #pragma unroll 4
    for (int c = 0; c < C; c += 4) {
        const float v0 = fb[(size_t)c * N + j];
        const float v1 = fb[(size_t)(c + 1) * N + j];
        const float v2 = fb[(size_t)(c + 2) * N + j];
        const float v3 = fb[(size_t)(c + 3) * N + j];
        out0[o0 + (size_t)c * MK]       = v0;
        out0[o0 + (size_t)(c + 1) * MK] = v1;
        out0[o0 + (size_t)(c + 2) * MK] = v2;
        out0[o0 + (size_t)(c + 3) * MK] = v3;
    }
}

extern "C" void kernel_launch(void* const* d_in, const int* in_sizes, int n_in,
                              void* d_out, int out_size, void* d_ws, size_t ws_size,
                              hipStream_t stream) {
    const float* new_xyz = (const float*)d_in[0];   // (B,3,M)
    const float* xyz     = (const float*)d_in[1];   // (B,3,N)
    const float* feat    = (const float*)d_in[2];   // (B,C,N)

    const int B = 4;                       // fixed by harness setup
    const int M = in_sizes[0] / (3 * B);   // 2048
    const int N = in_sizes[1] / (3 * B);   // 8192
    const int C = in_sizes[2] / (B * N);   // 128

    // out0 = group_feature (B,3+C,M,K) if use_xyz else (B,C,M,K); out1 = group_xyz (B,3,M,K)
    const long long sz_with = (long long)B * (C + 6) * M * K_NEIGH;
    const int use_xyz = (out_size == sz_with) ? 1 : 0;

    float* out0 = (float*)d_out;
    float* out1 = out0 + (size_t)B * (use_xyz ? (C + 3) : C) * M * K_NEIGH;

    int* idxb = (int*)d_ws;  // B*M*K ints = 1 MB

    ball_query_kernel<<<(B * M) / 4, 256, 0, stream>>>(xyz, new_xyz, idxb, N, M);
    gather_kernel<<<B * (M / 8), 256, 0, stream>>>(xyz, new_xyz, feat, idxb,
                                                   out0, out1, N, M, C, use_xyz);
}

// Round 2
// 93.279 us; speedup vs baseline: 1.6970x; 1.6970x over previous
//
#include <hip/hip_runtime.h>
#include <hip/hip_bf16.h>

// QueryGrouper: ball_query (first-K-in-index-order within radius) + grouping.
// B=4, N=8192, M=2048, C=128, K=32, radius=0.1, use_xyz from out_size.
//
// R2: transpose feature to (B,N,C) first so the per-neighbor gather reads are
// 512B-contiguous, then gather through a swizzled LDS tile so the (C,M,K)
// output stores stay coalesced. R1's direct gather (scattered 4B reads,
// 33.5M cacheline-wasting transactions) was latency-bound at 460 GB/s.

#define K_NEIGH 32
// f32(0.010000000000000002) — matches JAX weak-typed radius*radius bit-exactly.
#define R2_F32 0.009999999776482582f
#define CCH 128

__global__ __launch_bounds__(256) void ball_query_kernel(
    const float* __restrict__ xyz,      // (B,3,N)
    const float* __restrict__ new_xyz,  // (B,3,M)
    int* __restrict__ idxb,             // (B*M, K)
    int N, int M)
{
    const int wave = threadIdx.x >> 6;
    const int lane = threadIdx.x & 63;
    const int q = blockIdx.x * 4 + wave;           // query id in [0, B*M)
    const int b = q / M;
    const int m = q - b * M;

    const float* xb = xyz + (size_t)b * 3 * N;
    const float* nb = new_xyz + (size_t)b * 3 * M;
    const float qx = nb[m];
    const float qy = nb[M + m];
    const float qz = nb[2 * M + m];

    int* out = idxb + (size_t)q * K_NEIGH;

    int cnt = 0;
    int first_found = 0;   // pad value: first in-ball index, or 0 if none

    for (int t = 0; t < N; t += 64) {
        const int i = t + lane;
        // match JAX: sub, square (no FMA), left-to-right sum, all f32 RN
        const float dx = xb[i]         - qx;
        const float dy = xb[N + i]     - qy;
        const float dz = xb[2 * N + i] - qz;
        const float d2 = __fadd_rn(__fadd_rn(__fmul_rn(dx, dx), __fmul_rn(dy, dy)),
                                   __fmul_rn(dz, dz));
        const bool in_ball = d2 < R2_F32;
        const unsigned long long mask = __ballot(in_ball);
        if (mask) {
            if (cnt == 0) {
                first_found = t + (__ffsll((unsigned long long)mask) - 1);
            }
            if (in_ball) {
                const int pos = cnt + __popcll(mask & ((1ull << lane) - 1ull));
                if (pos < K_NEIGH) out[pos] = i;
            }
            cnt += __popcll(mask);
            if (cnt >= K_NEIGH) break;   // first K found (in index order)
        }
    }

    if (cnt < K_NEIGH) {
        if (lane >= cnt && lane < K_NEIGH) out[lane] = first_found;
    }
}

// feat (B,C,N) -> featT (B,N,C). 32x32 LDS tile, coalesced load & store.
__global__ __launch_bounds__(256) void transpose_kernel(
    const float* __restrict__ feat, float* __restrict__ featT, int N, int C)
{
    __shared__ float tl[32][33];
    const int tx = threadIdx.x & 31;
    const int ty = threadIdx.x >> 5;           // 0..7
    const int n0 = blockIdx.x * 32;
    const int c0 = blockIdx.y * 32;
    const int b  = blockIdx.z;

    const float* fb = feat + (size_t)b * C * N;
    #pragma unroll
    for (int r = 0; r < 32; r += 8)
        tl[ty + r][tx] = fb[(size_t)(c0 + ty + r) * N + n0 + tx];
    __syncthreads();
    float* fT = featT + (size_t)b * N * C;
    #pragma unroll
    for (int r = 0; r < 32; r += 8)
        fT[(size_t)(n0 + ty + r) * C + c0 + tx] = tl[tx][ty + r];
}

// One block per query. Loads 32 neighbor rows of featT (512B contiguous each),
// transposes through swizzled LDS, stores (C,M,K)-layout coalesced.
__global__ __launch_bounds__(256) void gather2_kernel(
    const float* __restrict__ xyz,      // (B,3,N)
    const float* __restrict__ new_xyz,  // (B,3,M)
    const float* __restrict__ featT,    // (B,N,C)
    const int* __restrict__ idxb,       // (B*M,K)
    float* __restrict__ out0,           // (B, 3+C or C, M, K)
    float* __restrict__ out1,           // (B, 3, M, K)
    int N, int M, int use_xyz)
{
    __shared__ float tile[CCH * K_NEIGH];   // [c][k], k XOR-swizzled; 16KB
    __shared__ int sidx[K_NEIGH];

    const int t = threadIdx.x;
    const int q = blockIdx.x;
    const int b = q / M;
    const int m = q - b * M;

    if (t < K_NEIGH) sidx[t] = idxb[(size_t)q * K_NEIGH + t];
    __syncthreads();

    const float* fT = featT + (size_t)b * N * CCH;

    // load phase: 1024 float4 = 32 rows x 32 float4; thread t -> f = t + r*256
    float4 v[4];
    int kk[4], c4[4];
    #pragma unroll
    for (int r = 0; r < 4; ++r) {
        const int f = t + r * 256;
        kk[r] = f >> 5;            // neighbor slot
        c4[r] = f & 31;            // float4 index within the 128-ch row
        const int j = sidx[kk[r]];
        v[r] = *(const float4*)(fT + (size_t)j * CCH + c4[r] * 4);
    }
    // LDS write, swizzle k' = k ^ ((c>>2)&31) = k ^ c4  -> bank = k^lane, conflict-free
    #pragma unroll
    for (int r = 0; r < 4; ++r) {
        const int cb = c4[r] * 4;
        const int kx = kk[r] ^ c4[r];
        tile[(cb + 0) * K_NEIGH + kx] = v[r].x;
        tile[(cb + 1) * K_NEIGH + kx] = v[r].y;
        tile[(cb + 2) * K_NEIGH + kx] = v[r].z;
        tile[(cb + 3) * K_NEIGH + kx] = v[r].w;
    }
    __syncthreads();

    const size_t MK = (size_t)M * K_NEIGH;

    // xyz part: 32 lanes, one per neighbor
    if (t < K_NEIGH) {
        const int j = sidx[t];
        const size_t xb  = (size_t)b * 3 * N;
        const size_t nbo = (size_t)b * 3 * M;
        const float gx = xyz[xb + j]         - new_xyz[nbo + m];
        const float gy = xyz[xb + N + j]     - new_xyz[nbo + M + m];
        const float gz = xyz[xb + 2 * N + j] - new_xyz[nbo + 2 * M + m];
        const size_t o1 = (size_t)b * 3 * MK + (size_t)m * K_NEIGH + t;
        out1[o1]          = gx;
        out1[o1 + MK]     = gy;
        out1[o1 + 2 * MK] = gz;
        if (use_xyz) {
            const size_t o0 = (size_t)b * (CCH + 3) * MK + (size_t)m * K_NEIGH + t;
            out0[o0]          = gx;
            out0[o0 + MK]     = gy;
            out0[o0 + 2 * MK] = gz;
        }
    }

    // feature part: per iter, 64-lane wave stores 2 channels x 32 k (2x128B)
    const int CO   = use_xyz ? (CCH + 3) : CCH;
    const int coff = use_xyz ? 3 : 0;
    const int k  = t & 31;
    const int cg = t >> 5;
    const size_t obase = ((size_t)b * CO + coff) * MK + (size_t)m * K_NEIGH + k;
    #pragma unroll
    for (int it = 0; it < 16; ++it) {
        const int c = it * 8 + cg;
        const float val = tile[c * K_NEIGH + (k ^ ((c >> 2) & 31))];
        out0[obase + (size_t)c * MK] = val;
    }
}

// R1 fallback gather (used only if ws too small or C != 128)
__global__ __launch_bounds__(256) void gather_kernel(
    const float* __restrict__ xyz, const float* __restrict__ new_xyz,
    const float* __restrict__ feat, const int* __restrict__ idxb,
    float* __restrict__ out0, float* __restrict__ out1,
    int N, int M, int C, int use_xyz)
{
    const int tid = threadIdx.x;
    const int k = tid & 31;
    const int mloc = tid >> 5;
    const int mchunks = M >> 3;
    const int b = blockIdx.x / mchunks;
    const int m = (blockIdx.x - b * mchunks) * 8 + mloc;
    const int q = b * M + m;
    const int j = idxb[(size_t)q * K_NEIGH + k];
    const size_t xb = (size_t)b * 3 * N;
    const size_t nb = (size_t)b * 3 * M;
    const float gx = xyz[xb + j]         - new_xyz[nb + m];
    const float gy = xyz[xb + N + j]     - new_xyz[nb + M + m];
    const float gz = xyz[xb + 2 * N + j] - new_xyz[nb + 2 * M + m];
    const size_t MK = (size_t)M * K_NEIGH;
    const size_t o1 = (size_t)b * 3 * MK + (size_t)m * K_NEIGH + k;
    out1[o1] = gx; out1[o1 + MK] = gy; out1[o1 + 2 * MK] = gz;
    const int CO = use_xyz ? (C + 3) : C;
    size_t o0 = (size_t)b * CO * MK + (size_t)m * K_NEIGH + k;
    if (use_xyz) {
        out0[o0] = gx; out0[o0 + MK] = gy; out0[o0 + 2 * MK] = gz;
        o0 += 3 * MK;
    }
    const float* fb = feat + (size_t)b * C * N;
    #pragma unroll 4
    for (int c = 0; c < C; c += 4) {
        const float v0 = fb[(size_t)c * N + j];
        const float v1 = fb[(size_t)(c + 1) * N + j];
        const float v2 = fb[(size_t)(c + 2) * N + j];
        const float v3 = fb[(size_t)(c + 3) * N + j];
        out0[o0 + (size_t)c * MK]       = v0;
        out0[o0 + (size_t)(c + 1) * MK] = v1;
        out0[o0 + (size_t)(c + 2) * MK] = v2;
        out0[o0 + (size_t)(c + 3) * MK] = v3;
    }
}

extern "C" void kernel_launch(void* const* d_in, const int* in_sizes, int n_in,
                              void* d_out, int out_size, void* d_ws, size_t ws_size,
                              hipStream_t stream) {
    const float* new_xyz = (const float*)d_in[0];   // (B,3,M)
    const float* xyz     = (const float*)d_in[1];   // (B,3,N)
    const float* feat    = (const float*)d_in[2];   // (B,C,N)

    const int B = 4;                       // fixed by harness setup
    const int M = in_sizes[0] / (3 * B);   // 2048
    const int N = in_sizes[1] / (3 * B);   // 8192
    const int C = in_sizes[2] / (B * N);   // 128

    const long long sz_with = (long long)B * (C + 6) * M * K_NEIGH;
    const int use_xyz = (out_size == sz_with) ? 1 : 0;

    float* out0 = (float*)d_out;
    float* out1 = out0 + (size_t)B * (use_xyz ? (C + 3) : C) * M * K_NEIGH;

    const size_t featT_bytes = (size_t)B * N * C * sizeof(float);
    const size_t idx_bytes   = (size_t)B * M * K_NEIGH * sizeof(int);
    const bool fast = (C == CCH) && (ws_size >= featT_bytes + idx_bytes)
                      && (N % 32 == 0) && (M % 8 == 0);

    if (fast) {
        float* featT = (float*)d_ws;
        int*   idxb  = (int*)((char*)d_ws + featT_bytes);
        ball_query_kernel<<<(B * M) / 4, 256, 0, stream>>>(xyz, new_xyz, idxb, N, M);
        transpose_kernel<<<dim3(N / 32, C / 32, B), 256, 0, stream>>>(feat, (float*)featT, N, C);
        gather2_kernel<<<B * M, 256, 0, stream>>>(xyz, new_xyz, featT, idxb,
                                                  out0, out1, N, M, use_xyz);
    } else {
        int* idxb = (int*)d_ws;
        ball_query_kernel<<<(B * M) / 4, 256, 0, stream>>>(xyz, new_xyz, idxb, N, M);
        gather_kernel<<<B * (M / 8), 256, 0, stream>>>(xyz, new_xyz, feat, idxb,
                                                       out0, out1, N, M, C, use_xyz);
    }
}

// Round 3
// 75.387 us; speedup vs baseline: 2.0998x; 1.2373x over previous
//
#include <hip/hip_runtime.h>
#include <hip/hip_bf16.h>

// QueryGrouper: ball_query (first-K-in-index-order within radius) + grouping.
// B=4, N=8192, M=2048, C=128, K=32, radius=0.1, use_xyz from out_size.
//
// R3: channel-staged gather. Block = (channel-pair, m-group, batch); stage the
// 2 channel rows (64KB) in LDS from feat directly (contiguous — transpose
// kernel eliminated), then idx-coalesced loop: ds_read_b64 per (m,k) gives
// both channels, stores are contiguous 256B/wave runs in (C,M,K) layout.
// XCD swizzle keeps each XCD's channel slab (2MB) L2-resident across its 8x
// re-reads. xyz/out1 fused into ball_query.

#define K_NEIGH 32
// f32(0.010000000000000002) — matches JAX weak-typed radius*radius bit-exactly.
#define R2_F32 0.009999999776482582f
#define CCH 128
#define NPTS 8192

__global__ __launch_bounds__(256) void ball_query_xyz_kernel(
    const float* __restrict__ xyz,      // (B,3,N)
    const float* __restrict__ new_xyz,  // (B,3,M)
    int* __restrict__ idxb,             // (B*M, K)
    float* __restrict__ out0,           // (B, CO, M, K)
    float* __restrict__ out1,           // (B, 3, M, K)
    int N, int M, int C, int use_xyz)
{
    __shared__ int lidx[4][K_NEIGH];
    const int wave = threadIdx.x >> 6;
    const int lane = threadIdx.x & 63;
    const int q = blockIdx.x * 4 + wave;           // query id in [0, B*M)
    const int b = q / M;
    const int m = q - b * M;

    const float* xb = xyz + (size_t)b * 3 * N;
    const float* nb = new_xyz + (size_t)b * 3 * M;
    const float qx = nb[m];
    const float qy = nb[M + m];
    const float qz = nb[2 * M + m];

    int cnt = 0;
    int first_found = 0;   // pad value: first in-ball index, or 0 if none

    for (int t0 = 0; t0 < N; t0 += 64) {
        const int i = t0 + lane;
        // match JAX: sub, square (no FMA), left-to-right sum, all f32 RN
        const float dx = xb[i]         - qx;
        const float dy = xb[N + i]     - qy;
        const float dz = xb[2 * N + i] - qz;
        const float d2 = __fadd_rn(__fadd_rn(__fmul_rn(dx, dx), __fmul_rn(dy, dy)),
                                   __fmul_rn(dz, dz));
        const bool in_ball = d2 < R2_F32;
        const unsigned long long mask = __ballot(in_ball);
        if (mask) {
            if (cnt == 0) {
                first_found = t0 + (__ffsll((unsigned long long)mask) - 1);
            }
            if (in_ball) {
                const int pos = cnt + __popcll(mask & ((1ull << lane) - 1ull));
                if (pos < K_NEIGH) lidx[wave][pos] = i;
            }
            cnt += __popcll(mask);
            if (cnt >= K_NEIGH) break;   // first K found (in index order)
        }
    }

    // per-wave LDS slice; only need our own wave's writes visible
    asm volatile("s_waitcnt lgkmcnt(0)" ::: "memory");

    if (lane < K_NEIGH) {
        const int j = (lane < cnt) ? lidx[wave][lane] : first_found;
        idxb[(size_t)q * K_NEIGH + lane] = j;
        const float gx = xb[j]         - qx;
        const float gy = xb[N + j]     - qy;
        const float gz = xb[2 * N + j] - qz;
        const size_t MK = (size_t)M * K_NEIGH;
        const size_t o1 = (size_t)b * 3 * MK + (size_t)m * K_NEIGH + lane;
        out1[o1]          = gx;
        out1[o1 + MK]     = gy;
        out1[o1 + 2 * MK] = gz;
        if (use_xyz) {
            const size_t o0 = (size_t)b * (C + 3) * MK + (size_t)m * K_NEIGH + lane;
            out0[o0]          = gx;
            out0[o0 + MK]     = gy;
            out0[o0 + 2 * MK] = gz;
        }
    }
}

// Fixed geometry fast path: B=4, N=8192, M=2048, C=128.
// grid = 2048 blocks: xcd = bid&7 owns channel-pairs [8*xcd, 8*xcd+8) for all
// batches (2MB slab -> L2-resident re-reads).
__global__ __launch_bounds__(256) void gather_chan_kernel(
    const float* __restrict__ feat,  // (B,C,N)
    const int* __restrict__ idxb,    // (B*M,K)
    float* __restrict__ out0,        // (B,CO,M,K)
    int use_xyz)
{
    __shared__ float sf[2 * NPTS];   // interleaved [j][2], 64 KB

    const int t   = threadIdx.x;
    const int bid = blockIdx.x;
    const int xcd = bid & 7;
    const int r   = bid >> 3;            // 0..255
    const int cg  = xcd * 8 + (r & 7);   // 0..63 channel-pair
    const int mg  = (r >> 3) & 7;        // 0..7 m-group of 256
    const int b   = r >> 6;              // 0..3

    const int c0 = cg * 2;
    const float* f0 = feat + ((size_t)b * CCH + c0) * NPTS;
    const float* f1 = f0 + NPTS;

    // stage both channel rows interleaved: sf[2*i] = c0, sf[2*i+1] = c0+1
    #pragma unroll
    for (int it = 0; it < NPTS / 256; ++it) {     // 32 iters
        const int i = t + it * 256;
        const float v0 = f0[i];
        const float v1 = f1[i];
        *(float2*)&sf[2 * i] = make_float2(v0, v1);
    }
    __syncthreads();

    const int M = 2048;
    const size_t MK = (size_t)M * K_NEIGH;
    const int CO   = use_xyz ? (CCH + 3) : CCH;
    const int coff = use_xyz ? 3 : 0;
    const int m0   = mg * 256;

    const int* ip = idxb + ((size_t)b * M + m0) * K_NEIGH;
    float* o = out0 + ((size_t)b * CO + coff + c0) * MK + (size_t)m0 * K_NEIGH;

    #pragma unroll 4
    for (int it = 0; it < (256 * K_NEIGH) / 256; ++it) {   // 32 iters
        const int item = t + it * 256;                     // (mloc<<5)|k
        const int j = ip[item];
        const float2 v = *(const float2*)&sf[2 * j];
        o[item]      = v.x;
        o[item + MK] = v.y;
    }
}

// Fallback gather (any shape): R1 structure.
__global__ __launch_bounds__(256) void gather_kernel(
    const float* __restrict__ xyz, const float* __restrict__ new_xyz,
    const float* __restrict__ feat, const int* __restrict__ idxb,
    float* __restrict__ out0, float* __restrict__ out1,
    int N, int M, int C, int use_xyz)
{
    const int tid = threadIdx.x;
    const int k = tid & 31;
    const int mloc = tid >> 5;
    const int mchunks = M >> 3;
    const int b = blockIdx.x / mchunks;
    const int m = (blockIdx.x - b * mchunks) * 8 + mloc;
    const int q = b * M + m;
    const int j = idxb[(size_t)q * K_NEIGH + k];
    const size_t xb = (size_t)b * 3 * N;
    const size_t nb = (size_t)b * 3 * M;
    const float gx = xyz[xb + j]         - new_xyz[nb + m];
    const float gy = xyz[xb + N + j]     - new_xyz[nb + M + m];
    const float gz = xyz[xb + 2 * N + j] - new_xyz[nb + 2 * M + m];
    const size_t MK = (size_t)M * K_NEIGH;
    const size_t o1 = (size_t)b * 3 * MK + (size_t)m * K_NEIGH + k;
    out1[o1] = gx; out1[o1 + MK] = gy; out1[o1 + 2 * MK] = gz;
    const int CO = use_xyz ? (C + 3) : C;
    size_t o0 = (size_t)b * CO * MK + (size_t)m * K_NEIGH + k;
    if (use_xyz) {
        out0[o0] = gx; out0[o0 + MK] = gy; out0[o0 + 2 * MK] = gz;
        o0 += 3 * MK;
    }
    const float* fb = feat + (size_t)b * C * N;
    #pragma unroll 4
    for (int c = 0; c < C; c += 4) {
        const float v0 = fb[(size_t)c * N + j];
        const float v1 = fb[(size_t)(c + 1) * N + j];
        const float v2 = fb[(size_t)(c + 2) * N + j];
        const float v3 = fb[(size_t)(c + 3) * N + j];
        out0[o0 + (size_t)c * MK]       = v0;
        out0[o0 + (size_t)(c + 1) * MK] = v1;
        out0[o0 + (size_t)(c + 2) * MK] = v2;
        out0[o0 + (size_t)(c + 3) * MK] = v3;
    }
}

extern "C" void kernel_launch(void* const* d_in, const int* in_sizes, int n_in,
                              void* d_out, int out_size, void* d_ws, size_t ws_size,
                              hipStream_t stream) {
    const float* new_xyz = (const float*)d_in[0];   // (B,3,M)
    const float* xyz     = (const float*)d_in[1];   // (B,3,N)
    const float* feat    = (const float*)d_in[2];   // (B,C,N)

    const int B = 4;                       // fixed by harness setup
    const int M = in_sizes[0] / (3 * B);   // 2048
    const int N = in_sizes[1] / (3 * B);   // 8192
    const int C = in_sizes[2] / (B * N);   // 128

    const long long sz_with = (long long)B * (C + 6) * M * K_NEIGH;
    const int use_xyz = (out_size == sz_with) ? 1 : 0;

    float* out0 = (float*)d_out;
    float* out1 = out0 + (size_t)B * (use_xyz ? (C + 3) : C) * M * K_NEIGH;

    int* idxb = (int*)d_ws;  // B*M*K ints = 1 MB
    const size_t idx_bytes = (size_t)B * M * K_NEIGH * sizeof(int);

    const bool fast = (B == 4) && (N == NPTS) && (M == 2048) && (C == CCH)
                      && (ws_size >= idx_bytes);

    ball_query_xyz_kernel<<<(B * M) / 4, 256, 0, stream>>>(
        xyz, new_xyz, idxb, out0, out1, N, M, C, use_xyz);

    if (fast) {
        gather_chan_kernel<<<2048, 256, 0, stream>>>(feat, idxb, out0, use_xyz);
    } else {
        gather_kernel<<<B * (M / 8), 256, 0, stream>>>(xyz, new_xyz, feat, idxb,
                                                       out0, out1, N, M, C, use_xyz);
    }
}